// Round 3
// baseline (160.871 us; speedup 1.0000x reference)
//
#include <hip/hip_runtime.h>
#include <math.h>

#define NATOMS    128
#define NSEG      7875
#define M_TRIU    8126      // (n*n-n)/2 - 2
#define PADLEN    8128      // M_TRIU + 2
#define OUT_PER_B 16256     // 2 * PADLEN
#define BLOCK     1024

struct F3 { float x, y, z; };
__device__ __forceinline__ F3 f3sub(F3 a, F3 b) { return {a.x - b.x, a.y - b.y, a.z - b.z}; }
__device__ __forceinline__ F3 f3cross(F3 a, F3 b) {
    return {a.y * b.z - a.z * b.y, a.z * b.x - a.x * b.z, a.x * b.y - a.y * b.x};
}
__device__ __forceinline__ float f3dot(F3 a, F3 b) { return a.x * b.x + a.y * b.y + a.z * b.z; }
// Single v_rsq_f32 (no IEEE fixup sequence): ~1 ulp, plenty for 5.9e-2 threshold.
__device__ __forceinline__ F3 f3norm(F3 a) {
    float rn = __builtin_amdgcn_rsqf(f3dot(a, a));
    return {a.x * rn, a.y * rn, a.z * rn};
}
__device__ __forceinline__ float clip1(float x) { return fminf(1.0f, fmaxf(-1.0f, x)); }

// Branchless asin, A&S 4.4.46 (|err| ~ 2e-8); single v_sqrt_f32.
__device__ __forceinline__ float fast_asin(float x) {
    float a = fabsf(x);
    float p = -0.0012624911f;
    p = fmaf(p, a,  0.0066700901f);
    p = fmaf(p, a, -0.0170881256f);
    p = fmaf(p, a,  0.0308918810f);
    p = fmaf(p, a, -0.0501743046f);
    p = fmaf(p, a,  0.0889789874f);
    p = fmaf(p, a, -0.2145988016f);
    p = fmaf(p, a,  1.5707963050f);
    float r = 1.57079632679f - __builtin_amdgcn_sqrtf(1.0f - a) * p;
    return copysignf(r, x);
}

// One block per batch; 16 waves/block, 2 blocks/CU => 32 waves/CU.
// LDS: 128*16 (float4 atoms) + 8126*4 (triu) ~= 34.5 KB; 2 blocks fit.
__global__ __launch_bounds__(BLOCK, 8) void writhe_fused(
    const float* __restrict__ xyz,       // (B, 128, 3)
    const int4*  __restrict__ segments,  // (7875, 4): i, i+1, j, j+1
    const int4*  __restrict__ indices,   // (7875, 4): triu slots (pidx-1)
    const int*   __restrict__ sortv,     // (16256,)
    float*       __restrict__ out)       // (B, 16256)
{
    __shared__ float4 sp[NATOMS];        // padded xyz -> one ds_read_b128/atom
    __shared__ float triu[M_TRIU];

    const int b = blockIdx.x;
    const int t = threadIdx.x;

    if (t < NATOMS) {
        const float* p = xyz + ((size_t)b * NATOMS + t) * 3;
        sp[t] = make_float4(p[0], p[1], p[2], 0.0f);
    }
    for (int m = t; m < M_TRIU; m += BLOCK) triu[m] = 0.0f;
    __syncthreads();

    for (int s = t; s < NSEG; s += BLOCK) {
        int4 seg = segments[s];
        int i = seg.x, j = seg.z;
        float4 q0 = sp[i];
        float4 q1 = sp[i + 1];
        float4 q2 = sp[j];
        float4 q3 = sp[j + 1];
        F3 p0 = {q0.x, q0.y, q0.z};
        F3 p1 = {q1.x, q1.y, q1.z};
        F3 p2 = {q2.x, q2.y, q2.z};
        F3 p3 = {q3.x, q3.y, q3.z};

        F3 d0 = f3norm(f3sub(p2, p0));
        F3 d1 = f3norm(f3sub(p3, p0));
        F3 d2 = f3norm(f3sub(p2, p1));
        F3 d3 = f3norm(f3sub(p3, p1));

        F3 axial = f3cross(f3sub(p3, p2), f3sub(p1, p0));
        float sd = f3dot(axial, d0);
        float sgn = (sd > 0.0f) ? 1.0f : ((sd < 0.0f) ? -1.0f : 0.0f);

        F3 n0 = f3norm(f3cross(d0, d1));
        F3 n1 = f3norm(f3cross(d1, d3));
        F3 n2 = f3norm(f3cross(d3, d2));
        F3 n3 = f3norm(f3cross(d2, d0));

        float c0 = clip1(f3dot(n0, n1));
        float c1 = clip1(f3dot(n1, n2));
        float c2 = clip1(f3dot(n2, n3));
        float c3 = clip1(f3dot(n3, n0));

        float omega = fast_asin(c0) + fast_asin(c1) + fast_asin(c2) + fast_asin(c3);
        float wr = omega * sgn * 0.15915494309189535f;  // / (2*pi)

        int4 idx = indices[s];
        atomicAdd(&triu[idx.x], wr);
        atomicAdd(&triu[idx.y], wr);
        atomicAdd(&triu[idx.z], wr);
        atomicAdd(&triu[idx.w], wr);
    }
    __syncthreads();

    float* ob = out + (size_t)b * OUT_PER_B;
    for (int k = t; k < OUT_PER_B; k += BLOCK) {
        int v = sortv[k];
        int p = (v >= PADLEN) ? (v - PADLEN) : v;
        float val = (p == 0 || p == PADLEN - 1) ? 0.0f : triu[p - 1];
        ob[k] = val;
    }
}

extern "C" void kernel_launch(void* const* d_in, const int* in_sizes, int n_in,
                              void* d_out, int out_size, void* d_ws, size_t ws_size,
                              hipStream_t stream) {
    const float* xyz      = (const float*)d_in[0];
    const int4*  segments = (const int4*)d_in[1];
    const int4*  indices  = (const int4*)d_in[2];
    const int*   sortv    = (const int*)d_in[3];
    float*       out      = (float*)d_out;

    int B = in_sizes[0] / (NATOMS * 3);   // 512 for the reference shapes
    writhe_fused<<<B, BLOCK, 0, stream>>>(xyz, segments, indices, sortv, out);
}

// Round 4
// 105.226 us; speedup vs baseline: 1.5288x; 1.5288x over previous
//
#include <hip/hip_runtime.h>
#include <math.h>

#define NATOMS    128
#define NSEG      7875     // segments: i in [0,124], j in [i+2,126]
#define M_TRIU    8126     // (n*n-n)/2 - 2
#define PADLEN    8128     // M_TRIU + 2
#define OUT_PER_B 16256    // 2 * PADLEN
#define BLOCK     1024

struct F3 { float x, y, z; };
__device__ __forceinline__ F3 f3sub(F3 a, F3 b) { return {a.x - b.x, a.y - b.y, a.z - b.z}; }
__device__ __forceinline__ F3 f3cross(F3 a, F3 b) {
    return {a.y * b.z - a.z * b.y, a.z * b.x - a.x * b.z, a.x * b.y - a.y * b.x};
}
__device__ __forceinline__ float f3dot(F3 a, F3 b) { return a.x * b.x + a.y * b.y + a.z * b.z; }
__device__ __forceinline__ F3 f3norm(F3 a) {
    float rn = __builtin_amdgcn_rsqf(f3dot(a, a));   // single v_rsq_f32
    return {a.x * rn, a.y * rn, a.z * rn};
}
__device__ __forceinline__ float clip1(float x) { return fminf(1.0f, fmaxf(-1.0f, x)); }

// Branchless asin, A&S 4.4.46 (|err| ~ 2e-8); single v_sqrt_f32.
__device__ __forceinline__ float fast_asin(float x) {
    float a = fabsf(x);
    float p = -0.0012624911f;
    p = fmaf(p, a,  0.0066700901f);
    p = fmaf(p, a, -0.0170881256f);
    p = fmaf(p, a,  0.0308918810f);
    p = fmaf(p, a, -0.0501743046f);
    p = fmaf(p, a,  0.0889789874f);
    p = fmaf(p, a, -0.2145988016f);
    p = fmaf(p, a,  1.5707963050f);
    float r = 1.57079632679f - __builtin_amdgcn_sqrtf(1.0f - a) * p;
    return copysignf(r, x);
}

// Segments-before-row-i: C(i) = 125*i - i*(i-1)/2
__device__ __forceinline__ int seg_row_base(int i) { return 125 * i - (i * (i - 1)) / 2; }
// Pair row base: base(a) = pidx(a, a+1) = a*(255-a)/2
__device__ __forceinline__ int pair_row_base(int a) { return (a * (255 - a)) / 2; }
// Segment id for (i,j), valid when 0<=i<=124, i+2<=j<=126
__device__ __forceinline__ int seg_id(int i, int j) { return seg_row_base(i) + (j - i - 2); }

// One block per batch. No VMEM and no atomics in the hot loop: (i,j) and all
// scatter topology derived analytically; scatter inverted to a gather.
// LDS: coords 1.5K + wr 31.5K + triu 32.5K ~= 65.6 KB; 2 blocks/CU (thread-limited).
__global__ __launch_bounds__(BLOCK, 8) void writhe_fused(
    const float* __restrict__ xyz,       // (B, 128, 3)
    const int*   __restrict__ sortv,     // (16256,)
    float*       __restrict__ out)       // (B, 16256)
{
    __shared__ float sx[NATOMS], sy[NATOMS], sz[NATOMS];
    __shared__ float swr[NSEG];
    __shared__ float triu[M_TRIU];

    const int b = blockIdx.x;
    const int t = threadIdx.x;

    // Stage coords (SoA). 384 scalar loads, coalesced enough for a one-time cost.
    if (t < 3 * NATOMS) {
        float v = xyz[(size_t)b * (3 * NATOMS) + t];
        int a = t / 3, c = t - 3 * a;
        if (c == 0) sx[a] = v; else if (c == 1) sy[a] = v; else sz[a] = v;
    }
    __syncthreads();

    // Phase A: wr per segment -> swr[s]. Zero VMEM, zero atomics.
    for (int s = t; s < NSEG; s += BLOCK) {
        // invert s -> (i, j): largest i with C(i) <= s
        int i = (int)((251.0f - __builtin_amdgcn_sqrtf(63001.0f - 8.0f * (float)s)) * 0.5f);
        while (seg_row_base(i + 1) <= s) ++i;      // fixup (0-1 iters)
        while (seg_row_base(i) > s) --i;
        int j = s - seg_row_base(i) + i + 2;

        F3 p0 = {sx[i],     sy[i],     sz[i]};
        F3 p1 = {sx[i + 1], sy[i + 1], sz[i + 1]};
        F3 p2 = {sx[j],     sy[j],     sz[j]};
        F3 p3 = {sx[j + 1], sy[j + 1], sz[j + 1]};

        F3 d0 = f3norm(f3sub(p2, p0));
        F3 d1 = f3norm(f3sub(p3, p0));
        F3 d2 = f3norm(f3sub(p2, p1));
        F3 d3 = f3norm(f3sub(p3, p1));

        F3 axial = f3cross(f3sub(p3, p2), f3sub(p1, p0));
        float sd = f3dot(axial, d0);
        float sgn = (sd > 0.0f) ? 1.0f : ((sd < 0.0f) ? -1.0f : 0.0f);

        F3 n0 = f3norm(f3cross(d0, d1));
        F3 n1 = f3norm(f3cross(d1, d3));
        F3 n2 = f3norm(f3cross(d3, d2));
        F3 n3 = f3norm(f3cross(d2, d0));

        float c0 = clip1(f3dot(n0, n1));
        float c1 = clip1(f3dot(n1, n2));
        float c2 = clip1(f3dot(n2, n3));
        float c3 = clip1(f3dot(n3, n0));

        float omega = fast_asin(c0) + fast_asin(c1) + fast_asin(c2) + fast_asin(c3);
        swr[s] = omega * sgn * 0.15915494309189535f;  // / (2*pi)
    }
    __syncthreads();

    // Phase B: gather-form Laplacian build. Slot m <-> pair (a,b); contributing
    // segments are (i,j) in {a-1,a} x {b-1,b} intersected with the valid range.
    for (int m = t; m < M_TRIU; m += BLOCK) {
        int q = m + 1;
        int a = (int)((255.0f - __builtin_amdgcn_sqrtf(65025.0f - 8.0f * (float)q)) * 0.5f);
        while (pair_row_base(a + 1) <= q) ++a;     // fixup (0-1 iters)
        while (pair_row_base(a) > q) --a;
        int bb = a + 1 + (q - pair_row_base(a));

        float sum = 0.0f;
        #pragma unroll
        for (int di = -1; di <= 0; ++di) {
            #pragma unroll
            for (int dj = -1; dj <= 0; ++dj) {
                int i = a + di, j = bb + dj;
                bool valid = (i >= 0) && (i <= 124) && (j >= i + 2) && (j <= 126);
                int s = valid ? seg_id(i, j) : 0;
                float v = swr[s];
                sum += valid ? v : 0.0f;
            }
        }
        triu[m] = sum;
    }
    __syncthreads();

    // Phase C: out[k] = padded2[sort[k]], padded2 = [0, triu, 0] twice.
    float* ob = out + (size_t)b * OUT_PER_B;
    for (int k = t; k < OUT_PER_B; k += BLOCK) {
        int v = sortv[k];
        int p = (v >= PADLEN) ? (v - PADLEN) : v;
        float val = (p == 0 || p == PADLEN - 1) ? 0.0f : triu[p - 1];
        ob[k] = val;
    }
}

extern "C" void kernel_launch(void* const* d_in, const int* in_sizes, int n_in,
                              void* d_out, int out_size, void* d_ws, size_t ws_size,
                              hipStream_t stream) {
    const float* xyz   = (const float*)d_in[0];
    const int*   sortv = (const int*)d_in[3];
    float*       out   = (float*)d_out;

    int B = in_sizes[0] / (NATOMS * 3);   // 512 for the reference shapes
    writhe_fused<<<B, BLOCK, 0, stream>>>(xyz, sortv, out);
}